// Round 11
// baseline (397.667 us; speedup 1.0000x reference)
//
#include <hip/hip_runtime.h>
#include <math.h>

#define NFAM 32
#define MREC 64
#define TSTRIDE 66                      // tile row stride: col 64 = count, 65 = pad
#define TILE_ELEMS (NFAM * TSTRIDE)     // 2112 floats = 8448 B
#define K1_BLOCKS 1024                  // 4 blocks/CU -> 32 waves/CU
#define K1_THREADS 512                  // 8 waves/block
#define K1_WAVES 8
#define K2_BLOCKS 33                    // 33 * 64 = 2112 tile elements

// ds_add_f32 on LDS: workgroup-scope relaxed fadd on a __shared__-derived
// pointer. (unsafeAtomicAdd took the flat-atomic slow path: rounds 3/7 = 165
// cyc/op serialized. Workgroup scope + addrspace(3) inference -> native DS add.)
__device__ __forceinline__ void lds_add(float* p, float v) {
    __hip_atomic_fetch_add(p, v, __ATOMIC_RELAXED, __HIP_MEMORY_SCOPE_WORKGROUP);
}

// ---------------------------------------------------------------------------
// K1: block-shared LDS tile (8.4 KB -> 4 blocks/CU), one row per wave-step:
// fam is wave-uniform (readlane -> SGPR), lane owns column `lane`, single
// ds_add_f32 per row (no RMW chain, addresses distinct per lane, 2-way bank
// alias = free). Counts via ballot into a register, flushed once.
// ---------------------------------------------------------------------------
__global__ __launch_bounds__(K1_THREADS) void mmi_accum(
    const float* __restrict__ activity,
    const int*   __restrict__ family_ids,
    float*       __restrict__ partial,   // [K1_BLOCKS][TILE_ELEMS]
    int*         __restrict__ ctr,       // K2 completion counter (zeroed here)
    int n_rows)
{
    __shared__ float tile[TILE_ELEMS];   // 8448 B, shared by all 8 waves
    const int tid = threadIdx.x;

    if (blockIdx.x == 0 && tid == 0) *ctr = 0;   // init K2's last-block counter

    for (int i = tid; i < TILE_ELEMS; i += K1_THREADS) tile[i] = 0.0f;
    __syncthreads();

    const int wave = tid >> 6;
    const int lane = tid & 63;
    float rc = 0.0f;                     // lane f (<32) counts family f

    const long long gw = (long long)blockIdx.x * K1_WAVES + wave;
    const long long nw = (long long)gridDim.x * K1_WAVES;

    // Each wave owns contiguous 64-row chunks (grid covers N exactly once).
    for (long long cb = gw * 64; cb < n_rows; cb += nw * 64) {
        if (cb + 64 <= n_rows) {
            // ---- fast path: full 64-row chunk ----
            const int ids = family_ids[cb + lane];           // 64 ids, one per lane
            const float* ap = activity + cb * MREC + lane;   // col `lane`
            #pragma unroll
            for (int b = 0; b < 8; ++b) {
                // 8 independent coalesced row-loads (256 B each) in flight
                const float v0 = ap[(b * 8 + 0) * MREC];
                const float v1 = ap[(b * 8 + 1) * MREC];
                const float v2 = ap[(b * 8 + 2) * MREC];
                const float v3 = ap[(b * 8 + 3) * MREC];
                const float v4 = ap[(b * 8 + 4) * MREC];
                const float v5 = ap[(b * 8 + 5) * MREC];
                const float v6 = ap[(b * 8 + 6) * MREC];
                const float v7 = ap[(b * 8 + 7) * MREC];
                // wave-uniform fam -> SGPR; one ds_add_f32 per row
                const int f0 = __builtin_amdgcn_readlane(ids, b * 8 + 0);
                lds_add(&tile[f0 * TSTRIDE + lane], v0);
                const int f1 = __builtin_amdgcn_readlane(ids, b * 8 + 1);
                lds_add(&tile[f1 * TSTRIDE + lane], v1);
                const int f2 = __builtin_amdgcn_readlane(ids, b * 8 + 2);
                lds_add(&tile[f2 * TSTRIDE + lane], v2);
                const int f3 = __builtin_amdgcn_readlane(ids, b * 8 + 3);
                lds_add(&tile[f3 * TSTRIDE + lane], v3);
                const int f4 = __builtin_amdgcn_readlane(ids, b * 8 + 4);
                lds_add(&tile[f4 * TSTRIDE + lane], v4);
                const int f5 = __builtin_amdgcn_readlane(ids, b * 8 + 5);
                lds_add(&tile[f5 * TSTRIDE + lane], v5);
                const int f6 = __builtin_amdgcn_readlane(ids, b * 8 + 6);
                lds_add(&tile[f6 * TSTRIDE + lane], v6);
                const int f7 = __builtin_amdgcn_readlane(ids, b * 8 + 7);
                lds_add(&tile[f7 * TSTRIDE + lane], v7);
            }
            // family counts via ballot (no per-row LDS traffic)
            for (int f = 0; f < NFAM; ++f) {
                const unsigned long long m = __ballot(ids == f);
                rc += (lane == f) ? (float)__popcll(m) : 0.0f;
            }
        } else {
            // ---- tail: per-row guarded (cold; N is a multiple of 64) ----
            for (int j = 0; j < 64; ++j) {
                const long long row = cb + j;
                if (row >= n_rows) break;
                const int fam = family_ids[row];
                lds_add(&tile[fam * TSTRIDE + lane], activity[row * MREC + lane]);
                rc += (lane == fam) ? 1.0f : 0.0f;
            }
        }
    }

    // flush per-wave counts (cross-wave shared tile -> atomic)
    if (lane < NFAM) lds_add(&tile[lane * TSTRIDE + 64], rc);
    __syncthreads();

    // one plain-store partial tile per block
    for (int e = tid; e < TILE_ELEMS; e += K1_THREADS)
        partial[(long long)blockIdx.x * TILE_ELEMS + e] = tile[e];
}

// ---------------------------------------------------------------------------
// K2: reduce K1_BLOCKS partial tiles -> final tile, then the LAST block
// (device-atomic counter) computes the double-precision entropy difference:
//   out = h_a_given_f - h_a = Sa - Sf/nfam
// ---------------------------------------------------------------------------
__global__ __launch_bounds__(256) void mmi_finalize(
    const float* __restrict__ partial,   // [K1_BLOCKS][TILE_ELEMS]
    float*       __restrict__ fin,       // [TILE_ELEMS]
    int*         __restrict__ ctr,
    float*       __restrict__ out)
{
    __shared__ float red[4][64];
    __shared__ int   lastflag;
    const int tid = threadIdx.x;
    const int sub = tid >> 6;            // 0..3: partial-stripe
    const int el  = tid & 63;
    const int e   = blockIdx.x * 64 + el;   // this block's 64 tile elements

    float s = 0.0f;
    for (int p = sub; p < K1_BLOCKS; p += 4)
        s += partial[(long long)p * TILE_ELEMS + e];
    red[sub][el] = s;
    __syncthreads();
    if (sub == 0) fin[e] = red[0][el] + red[1][el] + red[2][el] + red[3][el];

    // release partials-visibility, count this block done
    __threadfence();
    if (tid == 0) lastflag = (atomicAdd(ctr, 1) == gridDim.x - 1);
    __syncthreads();
    if (!lastflag) return;

    // ---- last block: acquire + entropy finalize ----
    __threadfence();
    __shared__ float ft[TILE_ELEMS];
    for (int i = tid; i < TILE_ELEMS; i += 256) ft[i] = fin[i];
    __syncthreads();

    if (tid < 64) {
        const int m = tid;
        double Ntot = 0.0;
        int nfam = 0;
        for (int f = 0; f < NFAM; ++f) {
            const double cf = (double)ft[f * TSTRIDE + 64];
            Ntot += cf;
            nfam += (cf > 0.0);
        }

        double T = 0.0;
        for (int f = 0; f < NFAM; ++f) T += (double)ft[f * TSTRIDE + m];
        const double mean = T / Ntot;
        const double ja = (1.0 - mean) * (1.0 - mean) + mean * mean;
        double la = log(ja);

        double lf = 0.0;
        for (int f = 0; f < NFAM; ++f) {
            const double cf = (double)ft[f * TSTRIDE + 64];
            if (cf > 0.0) {
                const double mf = (double)ft[f * TSTRIDE + m] / cf;
                const double jf = (1.0 - mf) * (1.0 - mf) + mf * mf;
                lf += log(jf);
            }
        }

        for (int off = 32; off > 0; off >>= 1) {
            la += __shfl_down(la, off, 64);
            lf += __shfl_down(lf, off, 64);
        }
        if (m == 0) out[0] = (float)(la - lf / (double)nfam);
    }
}

extern "C" void kernel_launch(void* const* d_in, const int* in_sizes, int n_in,
                              void* d_out, int out_size, void* d_ws, size_t ws_size,
                              hipStream_t stream) {
    const float* activity   = (const float*)d_in[0];
    const int*   family_ids = (const int*)d_in[1];
    float*       out        = (float*)d_out;

    const int n_rows = in_sizes[1];   // N = 524288

    float* partial = (float*)d_ws;                                    // 8.65 MB
    float* fin     = partial + (size_t)K1_BLOCKS * TILE_ELEMS;        // 8.4 KB
    int*   ctr     = (int*)(fin + TILE_ELEMS);

    mmi_accum<<<K1_BLOCKS, K1_THREADS, 0, stream>>>(activity, family_ids,
                                                    partial, ctr, n_rows);
    mmi_finalize<<<K2_BLOCKS, 256, 0, stream>>>(partial, fin, ctr, out);
}

// Round 14
// 353.098 us; speedup vs baseline: 1.1262x; 1.1262x over previous
//
#include <hip/hip_runtime.h>
#include <math.h>

#define NFAM 32
#define MREC 64
#define TSTR 65                          // tile row stride (bank-decorrelating pad)
#define CNT_OFF (NFAM * TSTR)            // 2080: counts live after the sums
#define TILE_ELEMS (CNT_OFF + NFAM)      // 2112 floats = 8448 B per wave tile
#define K1_BLOCKS 2048
#define K1_THREADS 256                   // 4 waves/block
#define K1_WAVES 4
#define K2_BLOCKS 33                     // 33*64 = 2112 elements

// ---------------------------------------------------------------------------
// K1: ZERO ATOMICS anywhere (LDS atomics = ~200cyc serialized on gfx950;
// rounds 3/7/11 all hit the same 176us wall; plain DS RMW (r10) was fast).
// Per-wave private 8.4KB tile. Each wave-step covers TWO rows:
//   lane = sub*32 + c ; one float2 load = rows {2s,2s+1} x all 64 cols (512B,
//   perfectly coalesced) ; both fams wave-uniform via readlane -> plain RMW
//   at per-lane-distinct LDS addresses. f0==f1 collision (p~1/32) merged via
//   shfl_down under a scalar branch. Counts via ballot into a register.
// ---------------------------------------------------------------------------
__global__ __launch_bounds__(K1_THREADS) void mmi_accum(
    const float* __restrict__ activity,
    const int*   __restrict__ family_ids,
    float*       __restrict__ partial,   // [K1_BLOCKS][TILE_ELEMS]
    int*         __restrict__ ctr,       // finalize's last-block counter
    int n_rows)
{
    __shared__ float lds[K1_WAVES][TILE_ELEMS];   // 4 * 8448 B = 33.8 KB
    const int tid = threadIdx.x;

    if (blockIdx.x == 0 && tid == 0) *ctr = 0;

    for (int i = tid; i < K1_WAVES * TILE_ELEMS; i += K1_THREADS)
        ((float*)lds)[i] = 0.0f;
    __syncthreads();

    const int wave = tid >> 6;
    const int lane = tid & 63;
    const int sub  = lane >> 5;          // which row of the pair
    const int c    = lane & 31;          // float2 column-pair (cols 2c, 2c+1)
    float* tile = lds[wave];
    float rc = 0.0f;                     // lane f (<32) counts family f

    const long long gw = (long long)blockIdx.x * K1_WAVES + wave;
    const long long nw = (long long)gridDim.x * K1_WAVES;

    for (long long cb = gw * 64; cb < n_rows; cb += nw * 64) {
        if (cb + 64 <= n_rows) {
            // ---- fast path: full 64-row chunk, 32 two-row steps ----
            const int ids = family_ids[cb + lane];            // 64 ids, 1/lane
            const float2* ap = (const float2*)(activity + cb * MREC) + c;
            #pragma unroll
            for (int b = 0; b < 4; ++b) {
                float2 v[8];
                #pragma unroll
                for (int j = 0; j < 8; ++j) {                 // 8 loads in flight
                    const int s = b * 8 + j;
                    v[j] = ap[(2 * s + sub) * (MREC / 2)];    // row 2s+sub, col 2c
                }
                #pragma unroll
                for (int j = 0; j < 8; ++j) {
                    const int s = b * 8 + j;
                    const int f0 = __builtin_amdgcn_readlane(ids, 2 * s);
                    const int f1 = __builtin_amdgcn_readlane(ids, 2 * s + 1);
                    if (f0 == f1) {                           // scalar branch
                        const float ax = v[j].x + __shfl_down(v[j].x, 32);
                        const float ay = v[j].y + __shfl_down(v[j].y, 32);
                        if (sub == 0) {
                            tile[f0 * TSTR + 2 * c + 0] += ax;
                            tile[f0 * TSTR + 2 * c + 1] += ay;
                        }
                    } else {
                        const int fs = sub ? f1 : f0;         // distinct addrs
                        tile[fs * TSTR + 2 * c + 0] += v[j].x;
                        tile[fs * TSTR + 2 * c + 1] += v[j].y;
                    }
                }
            }
            // family counts via ballot (no LDS traffic)
            for (int f = 0; f < NFAM; ++f) {
                const unsigned long long m = __ballot(ids == f);
                rc += (lane == f) ? (float)__popcll(m) : 0.0f;
            }
        } else {
            // ---- tail: per-row guarded (cold; N here is a multiple of 64) ----
            for (int j = 0; j < 64; ++j) {
                const long long row = cb + j;
                if (row >= n_rows) break;
                const int fam = family_ids[row];
                tile[fam * TSTR + lane] += activity[row * MREC + lane];
                rc += (lane == fam) ? 1.0f : 0.0f;
            }
        }
    }

    if (lane < NFAM) tile[CNT_OFF + lane] += rc;   // private tile, plain RMW
    __syncthreads();

    // one plain-store partial tile per block (no atomics)
    for (int e = tid; e < TILE_ELEMS; e += K1_THREADS)
        partial[(long long)blockIdx.x * TILE_ELEMS + e] =
            lds[0][e] + lds[1][e] + lds[2][e] + lds[3][e];
}

// ---------------------------------------------------------------------------
// K2: reduce K1_BLOCKS partial tiles -> final tile; LAST block (device-atomic
// counter) computes the double-precision entropy difference:
//   out = h_a_given_f - h_a = Sa - Sf/nfam
// ---------------------------------------------------------------------------
__global__ __launch_bounds__(256) void mmi_finalize(
    const float* __restrict__ partial,
    float*       __restrict__ fin,       // [TILE_ELEMS]
    int*         __restrict__ ctr,
    float*       __restrict__ out)
{
    __shared__ float red[4][64];
    __shared__ int   lastflag;
    const int tid = threadIdx.x;
    const int subw = tid >> 6;
    const int el   = tid & 63;
    const int e    = blockIdx.x * 64 + el;          // < 2112 (= 33*64) always

    float s = 0.0f;
    for (int p = subw; p < K1_BLOCKS; p += 4)
        s += partial[(long long)p * TILE_ELEMS + e];
    red[subw][el] = s;
    __syncthreads();
    if (subw == 0) fin[e] = red[0][el] + red[1][el] + red[2][el] + red[3][el];

    __threadfence();
    if (tid == 0) lastflag = (atomicAdd(ctr, 1) == gridDim.x - 1);
    __syncthreads();
    if (!lastflag) return;

    // ---- last block: entropy finalize in double ----
    __threadfence();
    __shared__ float ft[TILE_ELEMS];
    for (int i = tid; i < TILE_ELEMS; i += 256) ft[i] = fin[i];
    __syncthreads();

    if (tid < 64) {
        const int m = tid;
        double Ntot = 0.0;
        int nfam = 0;
        for (int f = 0; f < NFAM; ++f) {
            const double cf = (double)ft[CNT_OFF + f];
            Ntot += cf;
            nfam += (cf > 0.0);
        }

        double T = 0.0;
        for (int f = 0; f < NFAM; ++f) T += (double)ft[f * TSTR + m];
        const double mean = T / Ntot;
        const double ja = (1.0 - mean) * (1.0 - mean) + mean * mean;
        double la = log(ja);

        double lf = 0.0;
        for (int f = 0; f < NFAM; ++f) {
            const double cf = (double)ft[CNT_OFF + f];
            if (cf > 0.0) {
                const double mf = (double)ft[f * TSTR + m] / cf;
                const double jf = (1.0 - mf) * (1.0 - mf) + mf * mf;
                lf += log(jf);
            }
        }

        for (int off = 32; off > 0; off >>= 1) {
            la += __shfl_down(la, off, 64);
            lf += __shfl_down(lf, off, 64);
        }
        if (m == 0) out[0] = (float)(la - lf / (double)nfam);
    }
}

extern "C" void kernel_launch(void* const* d_in, const int* in_sizes, int n_in,
                              void* d_out, int out_size, void* d_ws, size_t ws_size,
                              hipStream_t stream) {
    const float* activity   = (const float*)d_in[0];
    const int*   family_ids = (const int*)d_in[1];
    float*       out        = (float*)d_out;

    const int n_rows = in_sizes[1];   // N = 524288

    float* partial = (float*)d_ws;                                    // 17.3 MB
    float* fin     = partial + (size_t)K1_BLOCKS * TILE_ELEMS;        // 8.4 KB
    int*   ctr     = (int*)(fin + TILE_ELEMS);

    mmi_accum<<<K1_BLOCKS, K1_THREADS, 0, stream>>>(activity, family_ids,
                                                    partial, ctr, n_rows);
    mmi_finalize<<<K2_BLOCKS, 256, 0, stream>>>(partial, fin, ctr, out);
}